// Round 1
// baseline (1262.072 us; speedup 1.0000x reference)
//
#include <hip/hip_runtime.h>

#define N_ 200000
#define E_ 6400000
#define F_ 128
#define H_ 16
#define C_ 10
#define B_ 512
#define NB_ ((N_ + 255) / 256)   // scan blocks = 782

// ---------------- CSR build ----------------

__global__ __launch_bounds__(256) void k_hist(const int* __restrict__ col, int* __restrict__ cnt) {
    int e = blockIdx.x * 256 + threadIdx.x;
    if (e < E_) atomicAdd(&cnt[col[e]], 1);
}

__global__ __launch_bounds__(256) void k_deg(const int* __restrict__ cnt, float* __restrict__ dis) {
    int i = blockIdx.x * 256 + threadIdx.x;
    if (i < N_) dis[i] = rsqrtf(1.0f + (float)cnt[i]);
}

__global__ __launch_bounds__(256) void k_scan_block(const int* __restrict__ cnt, int* __restrict__ blockSums) {
    __shared__ int s[256];
    int t = threadIdx.x;
    int i = blockIdx.x * 256 + t;
    s[t] = (i < N_) ? cnt[i] : 0;
    __syncthreads();
    for (int off = 128; off > 0; off >>= 1) {
        if (t < off) s[t] += s[t + off];
        __syncthreads();
    }
    if (t == 0) blockSums[blockIdx.x] = s[0];
}

__global__ __launch_bounds__(1024) void k_scan_top(int* __restrict__ blockSums) {
    __shared__ int s[1024];
    int t = threadIdx.x;
    s[t] = (t < NB_) ? blockSums[t] : 0;
    __syncthreads();
    for (int off = 1; off < 1024; off <<= 1) {
        int tmp = (t >= off) ? s[t - off] : 0;
        __syncthreads();
        s[t] += tmp;
        __syncthreads();
    }
    int excl = (t == 0) ? 0 : s[t - 1];
    if (t < NB_) blockSums[t] = excl;
}

__global__ __launch_bounds__(256) void k_scan_apply(const int* __restrict__ cnt, const int* __restrict__ blockSums,
                                                    int* __restrict__ offsets, int* __restrict__ cursor) {
    __shared__ int s[256];
    int t = threadIdx.x;
    int i = blockIdx.x * 256 + t;
    int v = (i < N_) ? cnt[i] : 0;
    s[t] = v;
    __syncthreads();
    for (int off = 1; off < 256; off <<= 1) {
        int tmp = (t >= off) ? s[t - off] : 0;
        __syncthreads();
        s[t] += tmp;
        __syncthreads();
    }
    int o = blockSums[blockIdx.x] + (s[t] - v);   // exclusive
    if (i < N_) { offsets[i] = o; cursor[i] = o; }
    if (i == 0) offsets[N_] = E_;
}

__global__ __launch_bounds__(256) void k_scatter(const int* __restrict__ row, const int* __restrict__ col,
                                                 int* __restrict__ cursor, int* __restrict__ row_sorted) {
    int e = blockIdx.x * 256 + threadIdx.x;
    if (e < E_) {
        int c = col[e];
        int p = atomicAdd(&cursor[c], 1);
        row_sorted[p] = row[e];
    }
}

// ---------------- dense parts ----------------

// hw[n][h] = sum_k x[n][k] * W1[k][h]     (x: [N,128], W1: [128,16])
__global__ __launch_bounds__(256) void k_gemm1(const float* __restrict__ x, const float* __restrict__ W1,
                                               float* __restrict__ hw) {
    __shared__ float w[F_ * H_];
    for (int i = threadIdx.x; i < F_ * H_; i += 256) w[i] = W1[i];
    __syncthreads();
    int n = blockIdx.x * 256 + threadIdx.x;
    if (n >= N_) return;
    float acc[H_];
#pragma unroll
    for (int h = 0; h < H_; ++h) acc[h] = 0.f;
    const float4* xr = reinterpret_cast<const float4*>(x + (size_t)n * F_);
#pragma unroll 4
    for (int k4 = 0; k4 < F_ / 4; ++k4) {
        float4 xv = xr[k4];
        int k = k4 * 4;
#pragma unroll
        for (int h = 0; h < H_; ++h) {
            acc[h] += xv.x * w[(k + 0) * H_ + h] + xv.y * w[(k + 1) * H_ + h]
                    + xv.z * w[(k + 2) * H_ + h] + xv.w * w[(k + 3) * H_ + h];
        }
    }
    float* o = hw + (size_t)n * H_;
#pragma unroll
    for (int h = 0; h < H_; h += 4)
        *(float4*)(o + h) = make_float4(acc[h], acc[h + 1], acc[h + 2], acc[h + 3]);
}

// hout[n][h] = sum_k hin[n][k] * W2[k][h]   (16x16)
__global__ __launch_bounds__(256) void k_gemm2(const float* __restrict__ hin, const float* __restrict__ W2,
                                               float* __restrict__ hout) {
    __shared__ float w[H_ * H_];
    if (threadIdx.x < H_ * H_) w[threadIdx.x] = W2[threadIdx.x];
    __syncthreads();
    int n = blockIdx.x * 256 + threadIdx.x;
    if (n >= N_) return;
    float hv[H_];
    const float4* hr = reinterpret_cast<const float4*>(hin + (size_t)n * H_);
#pragma unroll
    for (int q = 0; q < 4; ++q) {
        float4 v = hr[q];
        hv[q * 4 + 0] = v.x; hv[q * 4 + 1] = v.y; hv[q * 4 + 2] = v.z; hv[q * 4 + 3] = v.w;
    }
    float acc[H_];
#pragma unroll
    for (int h = 0; h < H_; ++h) acc[h] = 0.f;
#pragma unroll
    for (int k = 0; k < H_; ++k)
#pragma unroll
        for (int h = 0; h < H_; ++h) acc[h] += hv[k] * w[k * H_ + h];
    float* o = hout + (size_t)n * H_;
#pragma unroll
    for (int h = 0; h < H_; h += 4)
        *(float4*)(o + h) = make_float4(acc[h], acc[h + 1], acc[h + 2], acc[h + 3]);
}

// ---------------- aggregation (gather over CSR) ----------------
// out[n][h] = dis[n] * sum_{e in csr(n)} dis[row[e]] * hw[row[e]][h]
//           + hw[n][h] * dis[n]^2 + b[h]      (+ optional relu)
template <int RELU>
__global__ __launch_bounds__(256) void k_agg(const float* __restrict__ hw, const int* __restrict__ row_sorted,
                                             const int* __restrict__ offsets, const float* __restrict__ dis,
                                             const float* __restrict__ bias, float* __restrict__ out) {
    int t = blockIdx.x * 256 + threadIdx.x;
    int n = t >> 4;
    int h = t & 15;
    if (n >= N_) return;
    int s = offsets[n], e = offsets[n + 1];
    float accE = 0.f;
    for (int p = s; p < e; ++p) {
        int r = row_sorted[p];
        accE += dis[r] * hw[(size_t)r * H_ + h];
    }
    float dn = dis[n];
    float v = dn * accE + hw[(size_t)n * H_ + h] * dn * dn + bias[h];
    if (RELU) v = fmaxf(v, 0.f);
    out[(size_t)n * H_ + h] = v;
}

// ---------------- pool + fc ----------------
// one wave per graph; batch is sorted, binary-search the segment
__global__ __launch_bounds__(64) void k_pool_fc(const float* __restrict__ h2, const int* __restrict__ batch,
                                                const float* __restrict__ Wfc, const float* __restrict__ bfc,
                                                float* __restrict__ out) {
    int b = blockIdx.x;
    int lo = 0, hi = N_;
    while (lo < hi) { int m = (lo + hi) >> 1; if (batch[m] < b) lo = m + 1; else hi = m; }
    int start = lo;
    lo = start; hi = N_;
    while (lo < hi) { int m = (lo + hi) >> 1; if (batch[m] < b + 1) lo = m + 1; else hi = m; }
    int end = lo;

    int t = threadIdx.x;
    int h = t & 15, q = t >> 4;          // 4 node-lanes x 16 h-lanes
    float acc = 0.f;
    for (int n = start + q; n < end; n += 4) acc += h2[(size_t)n * H_ + h];
    acc += __shfl_xor(acc, 16);
    acc += __shfl_xor(acc, 32);

    __shared__ float pooled[H_];
    float cntf = fmaxf((float)(end - start), 1.0f);
    if (t < H_) pooled[t] = acc / cntf;
    __syncthreads();
    if (t < C_) {
        float o = bfc[t];
#pragma unroll
        for (int hh = 0; hh < H_; ++hh) o += pooled[hh] * Wfc[hh * C_ + t];
        out[b * C_ + t] = o;
    }
}

extern "C" void kernel_launch(void* const* d_in, const int* in_sizes, int n_in,
                              void* d_out, int out_size, void* d_ws, size_t ws_size,
                              hipStream_t stream) {
    const float* x    = (const float*)d_in[0];
    const int*   ei   = (const int*)d_in[1];        // [2*E]: row = ei, col = ei+E
    const int*   batch= (const int*)d_in[2];
    const float* W1   = (const float*)d_in[3];
    const float* b1   = (const float*)d_in[4];
    const float* W2   = (const float*)d_in[5];
    const float* b2   = (const float*)d_in[6];
    const float* Wfc  = (const float*)d_in[7];
    const float* bfc  = (const float*)d_in[8];
    float* out = (float*)d_out;

    const int* row = ei;
    const int* col = ei + E_;

    // workspace carve-up (≈54.5 MB)
    size_t off = 0;
    auto alloc = [&](size_t bytes) -> void* {
        void* p = (char*)d_ws + off;
        off += (bytes + 255) & ~(size_t)255;
        return p;
    };
    int*   cnt        = (int*)  alloc((size_t)N_ * 4);
    float* dis        = (float*)alloc((size_t)N_ * 4);
    int*   offsets    = (int*)  alloc((size_t)(N_ + 1) * 4);
    int*   cursor     = (int*)  alloc((size_t)N_ * 4);
    int*   blockSums  = (int*)  alloc((size_t)NB_ * 4);
    int*   row_sorted = (int*)  alloc((size_t)E_ * 4);
    float* hwA        = (float*)alloc((size_t)N_ * H_ * 4);
    float* hwB        = (float*)alloc((size_t)N_ * H_ * 4);
    (void)ws_size; (void)in_sizes; (void)n_in; (void)out_size;

    hipMemsetAsync(cnt, 0, (size_t)N_ * 4, stream);

    const int gridE = (E_ + 255) / 256;
    const int gridN = (N_ + 255) / 256;

    k_hist<<<gridE, 256, 0, stream>>>(col, cnt);
    k_deg<<<gridN, 256, 0, stream>>>(cnt, dis);
    k_scan_block<<<NB_, 256, 0, stream>>>(cnt, blockSums);
    k_scan_top<<<1, 1024, 0, stream>>>(blockSums);
    k_scan_apply<<<NB_, 256, 0, stream>>>(cnt, blockSums, offsets, cursor);
    k_scatter<<<gridE, 256, 0, stream>>>(row, col, cursor, row_sorted);

    k_gemm1<<<gridN, 256, 0, stream>>>(x, W1, hwA);                       // hwA = x@W1
    k_agg<1><<<(N_ * H_ + 255) / 256, 256, 0, stream>>>(hwA, row_sorted, offsets, dis, b1, hwB); // hwB = h1
    k_gemm2<<<gridN, 256, 0, stream>>>(hwB, W2, hwA);                     // hwA = h1@W2
    k_agg<0><<<(N_ * H_ + 255) / 256, 256, 0, stream>>>(hwA, row_sorted, offsets, dis, b2, hwB); // hwB = h2
    k_pool_fc<<<B_, 64, 0, stream>>>(hwB, batch, Wfc, bfc, out);
}